// Round 2
// 177.261 us; speedup vs baseline: 1.0264x; 1.0264x over previous
//
#include <hip/hip_runtime.h>

// Problem constants
constexpr int B = 32, C = 32, T = 2048, D = 512;
constexpr float ALPHA = 0.1f;
constexpr float BETA  = 0.9f;
constexpr float LOG2_BETA = -0.15200309344504997f;  // log2(0.9)
constexpr float BETA16    = 0.18530201888518410f;   // 0.9^16 (chunk carry factor)

// Native 4-float vector for __builtin_nontemporal_store.
typedef float floatx4 __attribute__((ext_vector_type(4)));

// Fused-kernel tiling.
// CHUNK=128, 8 sub-threads/channel of SUB=16 t each.
// Halo = one 16-chunk per sub-thread per side (128 total, beta^128 ~ 1.4e-6),
// computed COOPERATIVELY: each thread scans one halo chunk + its main chunk
// with zero init, publishes chunk sums L to LDS scratch, then composes its
// true carry via Horner with beta^16. Cuts halo LDS reads 256->32/thread.
// Staging window: wlo = t0-132 (multiple of 4 -> 16B-aligned float4 loads);
// WIN=388 exactly covers DD over [t0-129, t0+255] (fwd+bwd halo chunks).
// PAD=390: bank stride 6 -> 2-way aliasing (free, m136); rows 8B-aligned.
constexpr int CHUNK = 128;                  // t rows per block
constexpr int SUB   = 16;                   // t rows per thread (EWMA phase)
constexpr int NSUB  = CHUNK / SUB;          // 8 sub-threads per channel
constexpr int LEAD  = 132;                  // left margin: 128 halo + 1 diff + 3 align
constexpr int WIN   = LEAD + CHUNK + 128;   // 388 staged t per channel
constexpr int PAD   = WIN + 2;              // 390 LDS pitch

// ---------------------------------------------------------------------------
// Kernel 1: W_comb[e,c] = sum_d W_lin[e,d]*W_ve[d,c];
//           b_comb[e]   = sum_d W_lin[e,d]*b_ve[d] + b_lin[e]
// (out = smooth_C(diff) @ W_comb^T + b_comb -- EWMA commutes with Linear)
// ---------------------------------------------------------------------------
__global__ __launch_bounds__(256) void combine_weights(
    const float* __restrict__ W_ve, const float* __restrict__ b_ve,
    const float* __restrict__ W_lin, const float* __restrict__ b_lin,
    float* __restrict__ W_comb, float* __restrict__ b_comb) {
  int e  = blockIdx.x;
  int c  = threadIdx.x & 31;
  int ds = threadIdx.x >> 5;
  float acc = 0.f, accb = 0.f;
#pragma unroll 4
  for (int i = 0; i < 64; ++i) {
    int d = ds * 64 + i;
    float wl = W_lin[e * D + d];
    acc  += wl * W_ve[d * C + c];
    accb += wl * b_ve[d];
  }
  __shared__ float red[8][33];
  __shared__ float redb[8];
  red[ds][c] = acc;
  if (c == 0) redb[ds] = accb;
  __syncthreads();
  if (ds == 0) {
    float ssum = 0.f;
#pragma unroll
    for (int k = 0; k < 8; ++k) ssum += red[k][c];
    W_comb[e * C + c] = ssum;
    if (c == 0) {
      float sb = 0.f;
#pragma unroll
      for (int k = 0; k < 8; ++k) sb += redb[k];
      b_comb[e] = sb + b_lin[e];
    }
  }
}

// ---------------------------------------------------------------------------
// Kernel 2 (fused): diff + bidirectional EWMA in channel space + K=32 GEMM.
// grid = (T/CHUNK=16, B=32) = 512 blocks, 256 threads.
// ---------------------------------------------------------------------------
__global__ __launch_bounds__(256) void fused_main(
    const float* __restrict__ x, const float* __restrict__ W_comb,
    const float* __restrict__ b_comb, float* __restrict__ out) {
  int b   = blockIdx.y;
  int t0  = blockIdx.x * CHUNK;
  int wlo = t0 - LEAD;  // staged window covers global t in [wlo, wlo+WIN)

  __shared__ float xl[C * PAD];     // 48.75 KB; reused as s-tile in phase C
  __shared__ float Lf[2][NSUB][C];  // fwd chunk sums: [0]=halo [1]=main (2 KB)
  __shared__ float Lb[2][NSUB][C];  // bwd chunk sums (2 KB)
  const float* xb = x + (size_t)b * C * T;

  int c   = threadIdx.x & 31;
  int sub = threadIdx.x >> 5;

  // last-diff for the exact bwd init-term correction (L2-hot, hoisted early)
  float dlast = xb[c * T + (T - 1)] - xb[c * T + (T - 2)];

  // ---- Phase A: staging ----
  if (wlo >= 0 && wlo + WIN <= T) {
    // interior block (13 of 16): 16B-aligned float4 global loads (wlo%4==0),
    // paired ds_write_b64 (rows 8B-aligned since PAD is even).
    for (int idx = threadIdx.x; idx < C * (WIN / 4); idx += 256) {
      int cc = idx / (WIN / 4);  // compile-time divisor (97)
      int q  = idx - cc * (WIN / 4);
      float4 v   = *(const float4*)(xb + cc * T + wlo + 4 * q);
      float* dst = xl + cc * PAD + 4 * q;
      ((float2*)dst)[0] = make_float2(v.x, v.y);
      ((float2*)dst)[1] = make_float2(v.z, v.w);
    }
  } else {
    // edge block (bx 0,1,15): scalar clamped staging
    // (clamp makes DD(t)==0 exactly for t<=0 and t>=T).
    for (int idx = threadIdx.x; idx < C * WIN; idx += 256) {
      int cc = idx / WIN;  // compile-time divisor (388)
      int tt = idx - cc * WIN;
      int t  = min(max(wlo + tt, 0), T - 1);
      xl[cc * PAD + tt] = xb[cc * T + t];
    }
  }

  // W rows + bias into registers (overlaps staging latency)
  int li   = threadIdx.x & 127;
  int half = threadIdx.x >> 7;
  int e0   = li * 4;
  float w[4][C], bias[4];
#pragma unroll
  for (int j = 0; j < 4; ++j) {
    const float4* wr = (const float4*)(W_comb + (e0 + j) * C);
#pragma unroll
    for (int c4 = 0; c4 < C / 4; ++c4) {
      float4 wv = wr[c4];
      w[j][c4 * 4 + 0] = wv.x;
      w[j][c4 * 4 + 1] = wv.y;
      w[j][c4 * 4 + 2] = wv.z;
      w[j][c4 * 4 + 3] = wv.w;
    }
    bias[j] = b_comb[e0 + j];
  }
  __syncthreads();

  // ---- Phase B1: per-16-chunk local scans (zero-init): fwd+bwd, halo+main --
  int ts = t0 + sub * SUB;
  const float* xc = xl + c * PAD - wlo;  // index directly by global t
#define DD(t) (xc[(t)] - xc[(t) - 1])

  int ha = t0 - 128   + sub * SUB;  // this thread's fwd-halo chunk
  int ba = t0 + CHUNK + sub * SUB;  // this thread's bwd-halo chunk
  float fh = 0.f, bh = 0.f;
#pragma unroll
  for (int i = 0; i < SUB; ++i) {
    fh = ALPHA * DD(ha + i)           + BETA * fh;  // ascending
    bh = ALPHA * DD(ba + SUB - 1 - i) + BETA * bh;  // descending
  }
  float lr[SUB], rl[SUB];
  float fm = 0.f, bm = 0.f;
#pragma unroll
  for (int i = 0; i < SUB; ++i) {
    fm = ALPHA * DD(ts + i) + BETA * fm;
    lr[i] = fm;  // raw fwd scan (no carry yet)
    bm = ALPHA * DD(ts + SUB - 1 - i) + BETA * bm;
    rl[SUB - 1 - i] = bm;  // raw bwd scan
  }
  Lf[0][sub][c] = fh;
  Lf[1][sub][c] = lr[SUB - 1];
  Lb[0][sub][c] = bh;
  Lb[1][sub][c] = rl[0];
  __syncthreads();  // scratch visible; also: all xl reads done -> xl reusable
#undef DD

  // ---- Phase B2: Horner carry composition + in-register combine ----
  // S(t0-1)   = sum_h beta^(16(7-h)) Lf_halo[h];   carry into main sub s:
  // C_s = beta^(16s) S(t0-1) + sum_{j<s} beta^(16(s-1-j)) Lf_main[j]  (Horner)
  // B_s mirrored from the right (state at ts+16).
  float Cc = 0.f, Bc = 0.f;
#pragma unroll
  for (int h = 0; h < NSUB; ++h) {
    Cc = BETA16 * Cc + Lf[0][h][c];
    Bc = BETA16 * Bc + Lb[0][NSUB - 1 - h][c];
  }
#pragma unroll
  for (int j = 0; j < NSUB - 1; ++j) {  // predicated (sub-dependent trip)
    float cn = BETA16 * Cc + Lf[1][j][c];
    float bn = BETA16 * Bc + Lb[1][NSUB - 1 - j][c];
    Cc = (j < sub)            ? cn : Cc;
    Bc = (NSUB - 1 - j > sub) ? bn : Bc;
  }
  // lr_true[i] = lr_raw[i] + beta^(i+1) C_s ; rl_true[i] = rl_raw[i] + beta^(16-i) B_s
  // plus exact right-edge init term beta^(T-t) * d[T-1]  (since 1-ALPHA == BETA)
  float f = BETA * Cc;
#pragma unroll
  for (int i = 0; i < SUB; ++i) { lr[i] += f; f *= BETA; }
  float g = BETA * Bc;
  float e = exp2f((float)(T - ts - (SUB - 1)) * LOG2_BETA);  // beta^(T-te)
#pragma unroll
  for (int i = SUB - 1; i >= 0; --i) {
    lr[i] = 0.5f * (lr[i] + (rl[i] + g) + e * dlast);
    g *= BETA;
    e *= BETA;
  }

  // ---- Phase C: s-tile into reused LDS, then GEMM ----
  float* sbuf = xl;  // s[tloc*C + c], tloc in [0, CHUNK)
  {
    int tbase = sub * SUB;
#pragma unroll
    for (int i = 0; i < SUB; ++i) sbuf[(tbase + i) * C + c] = lr[i];
  }
  __syncthreads();

  const float* srow = sbuf + half * (CHUNK / 2) * C;
  float* orow = out + ((size_t)b * T + t0 + half * (CHUNK / 2)) * D + e0;

#pragma unroll 2
  for (int t = 0; t < CHUNK / 2; ++t) {
    float a[4], a2[4];
#pragma unroll
    for (int j = 0; j < 4; ++j) { a[j] = bias[j]; a2[j] = 0.f; }
    const float4* sr4 = (const float4*)(srow + t * C);
#pragma unroll
    for (int c4 = 0; c4 < C / 4; ++c4) {
      float4 sv = sr4[c4];  // broadcast ds_read_b128
      int cc = c4 * 4;
#pragma unroll
      for (int j = 0; j < 4; ++j) {
        a[j]  += sv.x * w[j][cc + 0];
        a2[j] += sv.y * w[j][cc + 1];
        a[j]  += sv.z * w[j][cc + 2];
        a2[j] += sv.w * w[j][cc + 3];
      }
    }
    floatx4 o;
    o.x = a[0] + a2[0];
    o.y = a[1] + a2[1];
    o.z = a[2] + a2[2];
    o.w = a[3] + a2[3];
    __builtin_nontemporal_store(o, (floatx4*)(orow + (size_t)t * D));
  }
}

// ---------------------------------------------------------------------------
extern "C" void kernel_launch(void* const* d_in, const int* in_sizes, int n_in,
                              void* d_out, int out_size, void* d_ws, size_t ws_size,
                              hipStream_t stream) {
  const float* x     = (const float*)d_in[0];  // [B,C,T]
  const float* W_ve  = (const float*)d_in[1];  // [D,C]
  const float* b_ve  = (const float*)d_in[2];  // [D]
  const float* W_lin = (const float*)d_in[3];  // [D,D]
  const float* b_lin = (const float*)d_in[4];  // [D]
  float* out = (float*)d_out;                  // [B,T,D]

  // workspace: W_comb [D*C], b_comb [D]
  float* W_comb = (float*)d_ws;
  float* b_comb = W_comb + (size_t)D * C;

  combine_weights<<<D, 256, 0, stream>>>(W_ve, b_ve, W_lin, b_lin, W_comb, b_comb);
  fused_main<<<dim3(T / CHUNK, B), 256, 0, stream>>>(x, W_comb, b_comb, out);
}